// Round 1
// baseline (413.503 us; speedup 1.0000x reference)
//
#include <hip/hip_runtime.h>
#include <cmath>

#define NB 64
#define ND 1024
#define DH 512
#define NL 2048
#define NCHUNK 16
#define RPB 128   // rows per block (L / NCHUNK)
#define RPW 32    // rows per wave
#define REC 520   // floats per (b,chunk,k) attn partial: [M, L, pad, pad, acc[512], pad]
#define KS 32     // GEMM k-split (4 blocks/CU -> 16 waves/CU latency hiding)

typedef float f4 __attribute__((ext_vector_type(4)));
__device__ __forceinline__ f4 ld4(const float* p) {
  return *(const f4*)p;   // cached path: the measured-6.3TB/s route (m13); NT never ubenched
}

// ---------------------------------------------------------------------------
// GEMM partials: part[ks][b][j] = sum_{k in slab} A[b][k] * W[j][k].
// A staged via LDS (coalesced float4, pad 36 keeps rows 16B-aligned). W rows
// are wave-uniform (all 64 lanes of a wave share the same 8 j) -> scalar-load
// path. Block = 64 b x 32 j (4 waves x 8 j). Grid (32 j-tiles, KS).
// ---------------------------------------------------------------------------
template <int KK>
__global__ __launch_bounds__(256, 4) void k_gemm(const float* __restrict__ A,
                                                 const float* __restrict__ W,
                                                 float* __restrict__ part) {
  constexpr int SLAB = KK / KS;   // 32 (KK=1024) or 64 (KK=2048)
  __shared__ float As[64][36];
  const int t = threadIdx.x;
  const int lane = t & 63;
  const int wv = t >> 6;
  const int k0 = blockIdx.y * SLAB;
  const int j0 = __builtin_amdgcn_readfirstlane((int)(blockIdx.x * 32 + wv * 8));
  const float* Wb = W + (size_t)j0 * KK + k0;

  float acc[8];
#pragma unroll
  for (int j = 0; j < 8; j++) acc[j] = 0.f;

  const int srow = t >> 2, sko = (t & 3) * 8;
  const float* sbase = A + (size_t)srow * KK + k0 + sko;

  for (int kc = 0; kc < SLAB; kc += 32) {
    float4 v0 = *(const float4*)(sbase + kc);
    float4 v1 = *(const float4*)(sbase + kc + 4);
    __syncthreads();   // protect previous chunk's readers
    *(float4*)&As[srow][sko]     = v0;
    *(float4*)&As[srow][sko + 4] = v1;
    __syncthreads();
#pragma unroll
    for (int kk = 0; kk < 32; kk += 4) {
      float4 av = *(const float4*)&As[lane][kk];
      const float* wp = Wb + kc + kk;
#pragma unroll
      for (int j = 0; j < 8; j++) {
        float4 wq = *(const float4*)(wp + (size_t)j * KK);   // uniform -> s_load
        acc[j] = fmaf(av.x, wq.x, acc[j]);
        acc[j] = fmaf(av.y, wq.y, acc[j]);
        acc[j] = fmaf(av.z, wq.z, acc[j]);
        acc[j] = fmaf(av.w, wq.w, acc[j]);
      }
    }
  }
  float* p = part + ((size_t)blockIdx.y * 64 + lane) * ND + j0;
  *(float4*)(p)     = make_float4(acc[0], acc[1], acc[2], acc[3]);
  *(float4*)(p + 4) = make_float4(acc[4], acc[5], acc[6], acc[7]);
}

// Sum KS partials -> out, optional tanh. 64*1024 floats, grid 256 x 64.
template <int ACT>
__global__ __launch_bounds__(64) void k_reduce(const float* __restrict__ part,
                                               float* __restrict__ out) {
  const int i = (blockIdx.x * 64 + threadIdx.x) * 4;
  float4 s = make_float4(0.f, 0.f, 0.f, 0.f);
#pragma unroll 8
  for (int ks = 0; ks < KS; ks++) {
    float4 v = *(const float4*)(part + (size_t)ks * (64 * ND) + i);
    s.x += v.x; s.y += v.y; s.z += v.z; s.w += v.w;
  }
  if (ACT) { s.x = tanhf(s.x); s.y = tanhf(s.y); s.z = tanhf(s.z); s.w = tanhf(s.w); }
  *(float4*)(out + i) = s;
}

// ---------------------------------------------------------------------------
// Fused attention pass: context read ONCE (cached loads). Batch-2 rows per
// step (4 independent butterfly chains), depth-2-row register prefetch.
// Deferred exact rescale: post-butterfly scores are wave-uniform, so the
// rescale branch is runtime-uniform (s_cbranch skips it when max doesn't
// grow) -> common path is 2 exp + 16 fma per k per 2 rows.
// ---------------------------------------------------------------------------
__global__ __launch_bounds__(256, 4) void k2_attn(const float* __restrict__ ctx,
                                                  const float* __restrict__ tgt,
                                                  float* __restrict__ sc0,
                                                  float* __restrict__ sc1,
                                                  float* __restrict__ part) {
  const int chunk = blockIdx.x, b = blockIdx.y;
  const int wave = threadIdx.x >> 6, lane = threadIdx.x & 63;
  const float* crow = ctx + ((size_t)b * NL + chunk * RPB + wave * RPW) * DH + lane * 8;

  // Lane owns d = 8*lane + j. target row interleaved (2d+k).
  float t0[8], t1[8];
  {
    const float* tp = tgt + b * ND + lane * 16;
#pragma unroll
    for (int j = 0; j < 4; j++) {
      float4 v = *(const float4*)(tp + j * 4);
      t0[2 * j] = v.x; t1[2 * j] = v.y; t0[2 * j + 1] = v.z; t1[2 * j + 1] = v.w;
    }
  }

  float m0 = -INFINITY, l0 = 0.f, m1 = -INFINITY, l1 = 0.f;
  float a0[8], a1[8];
#pragma unroll
  for (int j = 0; j < 8; j++) { a0[j] = 0.f; a1[j] = 0.f; }
  float sv0 = 0.f, sv1 = 0.f;

  f4 cur[4], nxt[4];   // 2 rows x 32B
  cur[0] = ld4(crow);
  cur[1] = ld4(crow + 4);
  cur[2] = ld4(crow + DH);
  cur[3] = ld4(crow + DH + 4);

#pragma unroll 2
  for (int ib = 0; ib < 16; ib++) {
    if (ib < 15) {
      const float* p = crow + (size_t)(2 * ib + 2) * DH;
      nxt[0] = ld4(p);
      nxt[1] = ld4(p + 4);
      nxt[2] = ld4(p + DH);
      nxt[3] = ld4(p + DH + 4);
    }
    const float* C = (const float*)cur;   // C[r*8+j], r in {0,1}

    float s0[2], s1[2];
#pragma unroll
    for (int r = 0; r < 2; r++) {
      float x0 = 0.f, x1 = 0.f;
#pragma unroll
      for (int j = 0; j < 8; j++) { x0 += C[r * 8 + j] * t0[j]; x1 += C[r * 8 + j] * t1[j]; }
      s0[r] = x0; s1[r] = x1;
    }
    // 4 independent butterfly chains (latency pipelined)
#pragma unroll
    for (int off = 32; off; off >>= 1) {
      s0[0] += __shfl_xor(s0[0], off);
      s0[1] += __shfl_xor(s0[1], off);
      s1[0] += __shfl_xor(s1[0], off);
      s1[1] += __shfl_xor(s1[1], off);
    }
#pragma unroll
    for (int r = 0; r < 2; r++)
      if (lane == 2 * ib + r) { sv0 = s0[r]; sv1 = s1[r]; }

    // k=0: deferred exact rescale (branch is wave-uniform at runtime)
    {
      float mx = fmaxf(s0[0], s0[1]);
      if (mx > m0) {
        float al = __expf(m0 - mx);
        l0 *= al;
#pragma unroll
        for (int j = 0; j < 8; j++) a0[j] *= al;
        m0 = mx;
      }
      float p0 = __expf(s0[0] - m0), p1 = __expf(s0[1] - m0);
      l0 += p0 + p1;
#pragma unroll
      for (int j = 0; j < 8; j++)
        a0[j] = fmaf(p1, C[8 + j], fmaf(p0, C[j], a0[j]));
    }
    // k=1
    {
      float mx = fmaxf(s1[0], s1[1]);
      if (mx > m1) {
        float al = __expf(m1 - mx);
        l1 *= al;
#pragma unroll
        for (int j = 0; j < 8; j++) a1[j] *= al;
        m1 = mx;
      }
      float p0 = __expf(s1[0] - m1), p1 = __expf(s1[1] - m1);
      l1 += p0 + p1;
#pragma unroll
      for (int j = 0; j < 8; j++)
        a1[j] = fmaf(p1, C[8 + j], fmaf(p0, C[j], a1[j]));
    }
#pragma unroll
    for (int i = 0; i < 4; i++) cur[i] = nxt[i];
  }

  const int rowbase = b * NL + chunk * RPB + wave * RPW;
  if (lane < RPW) { sc0[rowbase + lane] = sv0; sc1[rowbase + lane] = sv1; }

  // merge 4 waves in LDS (vectorized: 4x ds_write_b128 instead of 16 scalar)
  __shared__ float accS[4][1024];
  __shared__ float mlS[4][4];
  *(float4*)&accS[wave][lane * 8]           = make_float4(a0[0], a0[1], a0[2], a0[3]);
  *(float4*)&accS[wave][lane * 8 + 4]       = make_float4(a0[4], a0[5], a0[6], a0[7]);
  *(float4*)&accS[wave][512 + lane * 8]     = make_float4(a1[0], a1[1], a1[2], a1[3]);
  *(float4*)&accS[wave][512 + lane * 8 + 4] = make_float4(a1[4], a1[5], a1[6], a1[7]);
  if (lane == 0) { mlS[wave][0] = m0; mlS[wave][1] = l0; mlS[wave][2] = m1; mlS[wave][3] = l1; }
  __syncthreads();

  const int t = threadIdx.x;
  const int k = (t * 4) >> 9;
  const int d = (t * 4) & 511;
  float M = fmaxf(fmaxf(mlS[0][2 * k], mlS[1][2 * k]), fmaxf(mlS[2][2 * k], mlS[3][2 * k]));
  float Lk = 0.f;
  float v0 = 0.f, v1 = 0.f, v2 = 0.f, v3 = 0.f;
#pragma unroll
  for (int w = 0; w < 4; w++) {
    float e = __expf(mlS[w][2 * k] - M);
    Lk += mlS[w][2 * k + 1] * e;
    const float* ap = &accS[w][k * 512 + d];
    v0 += ap[0] * e; v1 += ap[1] * e; v2 += ap[2] * e; v3 += ap[3] * e;
  }
  float* rec = part + ((size_t)(b * NCHUNK + chunk) * 2 + k) * REC;
  if ((t & 127) == 0) { rec[0] = M; rec[1] = Lk; }
  *(float4*)&rec[4 + d] = make_float4(v0, v1, v2, v3);
}

// ---------------------------------------------------------------------------
// Merge NCHUNK attn partials -> combined row [w0|w1|input]; normalize raw
// scores in place. Grid 256 = 64 b x 4 quadrants.
// ---------------------------------------------------------------------------
__global__ __launch_bounds__(256) void k3_combine(const float* __restrict__ part,
                                                  const float* __restrict__ inp,
                                                  float* __restrict__ combined,
                                                  float* __restrict__ sc0,
                                                  float* __restrict__ sc1) {
  const int b = blockIdx.x >> 2, q = blockIdx.x & 3;
  const int t = threadIdx.x;
  __shared__ float MM[2], LL[2];
  __shared__ float eS[2][NCHUNK];
  if (t < 2) {
    const int k = t;
    float Mk = -INFINITY;
#pragma unroll
    for (int c = 0; c < NCHUNK; c++)
      Mk = fmaxf(Mk, part[((size_t)(b * NCHUNK + c) * 2 + k) * REC]);
    float Lk = 0.f;
#pragma unroll
    for (int c = 0; c < NCHUNK; c++) {
      const float* rec = part + ((size_t)(b * NCHUNK + c) * 2 + k) * REC;
      Lk += rec[1] * __expf(rec[0] - Mk);
    }
    MM[k] = Mk; LL[k] = Lk;
  }
  __syncthreads();
  if (t < 2 * NCHUNK) {
    const int k = t >> 4, c = t & 15;
    eS[k][c] = __expf(part[((size_t)(b * NCHUNK + c) * 2 + k) * REC] - MM[k]);
  }
  __syncthreads();

  const int k = t >> 7, d = q * 128 + (t & 127);
  float v = 0.f;
#pragma unroll
  for (int c = 0; c < NCHUNK; c++)
    v += part[((size_t)(b * NCHUNK + c) * 2 + k) * REC + 4 + d] * eS[k][c];
  combined[(size_t)b * 2048 + k * 512 + d] = v / LL[k];

  combined[(size_t)b * 2048 + 1024 + q * 256 + t] = inp[(size_t)b * ND + q * 256 + t];

  const float M0 = MM[0], i0 = 1.f / LL[0];
  const float M1 = MM[1], i1 = 1.f / LL[1];
  const int pos = b * NL + q * 512 + t * 2;
  float2 x0 = *(const float2*)(sc0 + pos);
  float2 x1 = *(const float2*)(sc1 + pos);
  x0.x = __expf(x0.x - M0) * i0; x0.y = __expf(x0.y - M0) * i0;
  x1.x = __expf(x1.x - M1) * i1; x1.y = __expf(x1.y - M1) * i1;
  *(float2*)(sc0 + pos) = x0;
  *(float2*)(sc1 + pos) = x1;
}

// ---------------------------------------------------------------------------
extern "C" void kernel_launch(void* const* d_in, const int* in_sizes, int n_in,
                              void* d_out, int out_size, void* d_ws, size_t ws_size,
                              hipStream_t stream) {
  const float* input   = (const float*)d_in[0];   // [64,1024]
  const float* context = (const float*)d_in[1];   // [64,2048,512]
  const float* W_in    = (const float*)d_in[2];   // [1024,1024]
  const float* W_out   = (const float*)d_in[3];   // [1024,2048]

  float* out   = (float*)d_out;        // [64,1024] contextOutput
  float* attn0 = out + NB * ND;        // [64,2048]
  float* attn1 = attn0 + NB * NL;      // [64,2048]

  float* ws       = (float*)d_ws;
  float* target   = ws;                               // 64*1024
  float* combined = target + NB * ND;                 // 64*2048
  float* apart    = combined + NB * 2048;             // 64*16*2*520
  float* gpart    = apart + NB * NCHUNK * 2 * REC;    // KS*64*1024

  // 1) target = input @ W_in.T   (split-K partials + reduce)
  k_gemm<ND><<<dim3(32, KS), dim3(256), 0, stream>>>(input, W_in, gpart);
  k_reduce<0><<<dim3(256), dim3(64), 0, stream>>>(gpart, target);
  // 2) fused scores + online-softmax weighted partials (context read once)
  k2_attn<<<dim3(NCHUNK, NB), dim3(256), 0, stream>>>(context, target, attn0, attn1, apart);
  // 3) merge partials -> combined rows; normalize attn in place
  k3_combine<<<dim3(4 * NB), dim3(256), 0, stream>>>(apart, input, combined, attn0, attn1);
  // 4) out = tanh(combined @ W_out.T)
  k_gemm<2 * ND><<<dim3(32, KS), dim3(256), 0, stream>>>(combined, W_out, gpart);
  k_reduce<1><<<dim3(256), dim3(64), 0, stream>>>(gpart, out);
}

// Round 2
// 392.534 us; speedup vs baseline: 1.0534x; 1.0534x over previous
//
#include <hip/hip_runtime.h>
#include <cmath>

#define NB 64
#define ND 1024
#define DH 512
#define NL 2048
#define NCHUNK 16
#define RPB 128   // rows per block (L / NCHUNK)
#define RPW 32    // rows per wave
#define REC 520   // floats per (b,chunk,k) attn partial: [M, L, pad, pad, acc[512], pad]
#define KS 32     // GEMM k-split (4 blocks/CU -> 16 waves/CU latency hiding)

typedef float f4 __attribute__((ext_vector_type(4)));
__device__ __forceinline__ f4 ntld(const float* p) {
  return __builtin_nontemporal_load((const f4*)p);
}

// ---------------------------------------------------------------------------
// GEMM partials: part[ks][b][j] = sum_{k in slab} A[b][k] * W[j][k].
// A staged via LDS (coalesced float4, pad 36 keeps rows 16B-aligned). W rows
// are wave-uniform (all 64 lanes of a wave share the same 8 j) -> scalar-load
// path. Block = 64 b x 32 j (4 waves x 8 j). Grid (32 j-tiles, KS).
// ---------------------------------------------------------------------------
template <int KK>
__global__ __launch_bounds__(256, 4) void k_gemm(const float* __restrict__ A,
                                                 const float* __restrict__ W,
                                                 float* __restrict__ part) {
  constexpr int SLAB = KK / KS;   // 32 (KK=1024) or 64 (KK=2048)
  __shared__ float As[64][36];
  const int t = threadIdx.x;
  const int lane = t & 63;
  const int wv = t >> 6;
  const int k0 = blockIdx.y * SLAB;
  const int j0 = __builtin_amdgcn_readfirstlane((int)(blockIdx.x * 32 + wv * 8));
  const float* Wb = W + (size_t)j0 * KK + k0;

  float acc[8];
#pragma unroll
  for (int j = 0; j < 8; j++) acc[j] = 0.f;

  const int srow = t >> 2, sko = (t & 3) * 8;
  const float* sbase = A + (size_t)srow * KK + k0 + sko;

  for (int kc = 0; kc < SLAB; kc += 32) {
    float4 v0 = *(const float4*)(sbase + kc);
    float4 v1 = *(const float4*)(sbase + kc + 4);
    __syncthreads();   // protect previous chunk's readers
    *(float4*)&As[srow][sko]     = v0;
    *(float4*)&As[srow][sko + 4] = v1;
    __syncthreads();
#pragma unroll
    for (int kk = 0; kk < 32; kk += 4) {
      float4 av = *(const float4*)&As[lane][kk];
      const float* wp = Wb + kc + kk;
#pragma unroll
      for (int j = 0; j < 8; j++) {
        float4 wq = *(const float4*)(wp + (size_t)j * KK);   // uniform -> s_load
        acc[j] = fmaf(av.x, wq.x, acc[j]);
        acc[j] = fmaf(av.y, wq.y, acc[j]);
        acc[j] = fmaf(av.z, wq.z, acc[j]);
        acc[j] = fmaf(av.w, wq.w, acc[j]);
      }
    }
  }
  float* p = part + ((size_t)blockIdx.y * 64 + lane) * ND + j0;
  *(float4*)(p)     = make_float4(acc[0], acc[1], acc[2], acc[3]);
  *(float4*)(p + 4) = make_float4(acc[4], acc[5], acc[6], acc[7]);
}

// Sum KS partials -> out, optional tanh. 64*1024 floats, grid 256 x 64.
// gpart is dead after this read -> nontemporal (no L2/L3 re-allocation).
template <int ACT>
__global__ __launch_bounds__(64) void k_reduce(const float* __restrict__ part,
                                               float* __restrict__ out) {
  const int i = (blockIdx.x * 64 + threadIdx.x) * 4;
  float4 s = make_float4(0.f, 0.f, 0.f, 0.f);
#pragma unroll 8
  for (int ks = 0; ks < KS; ks++) {
    f4 v = ntld(part + (size_t)ks * (64 * ND) + i);
    s.x += v.x; s.y += v.y; s.z += v.z; s.w += v.w;
  }
  if (ACT) { s.x = tanhf(s.x); s.y = tanhf(s.y); s.z = tanhf(s.z); s.w = tanhf(s.w); }
  *(float4*)(out + i) = s;
}

// ---------------------------------------------------------------------------
// Fused attention pass: context read ONCE (nontemporal — 256MB stream must
// not allocate through L2/L3; round-1 A/B showed cached loads cost ~20us).
// Batch-2 rows per step (4 independent butterfly chains), depth-2-row
// register prefetch. Unconditional rescale: branchless hot loop keeps the
// compiler's load pipelining intact (round-1 deferred-rescale regressed).
// ---------------------------------------------------------------------------
__global__ __launch_bounds__(256, 4) void k2_attn(const float* __restrict__ ctx,
                                                  const float* __restrict__ tgt,
                                                  float* __restrict__ sc0,
                                                  float* __restrict__ sc1,
                                                  float* __restrict__ part) {
  const int chunk = blockIdx.x, b = blockIdx.y;
  const int wave = threadIdx.x >> 6, lane = threadIdx.x & 63;
  const float* crow = ctx + ((size_t)b * NL + chunk * RPB + wave * RPW) * DH + lane * 8;

  // Lane owns d = 8*lane + j. target row interleaved (2d+k).
  float t0[8], t1[8];
  {
    const float* tp = tgt + b * ND + lane * 16;
#pragma unroll
    for (int j = 0; j < 4; j++) {
      float4 v = *(const float4*)(tp + j * 4);
      t0[2 * j] = v.x; t1[2 * j] = v.y; t0[2 * j + 1] = v.z; t1[2 * j + 1] = v.w;
    }
  }

  float m0 = -INFINITY, l0 = 0.f, m1 = -INFINITY, l1 = 0.f;
  float a0[8], a1[8];
#pragma unroll
  for (int j = 0; j < 8; j++) { a0[j] = 0.f; a1[j] = 0.f; }
  float sv0 = 0.f, sv1 = 0.f;

  f4 cur[4], nxt[4];   // 2 rows x 32B
  cur[0] = ntld(crow);
  cur[1] = ntld(crow + 4);
  cur[2] = ntld(crow + DH);
  cur[3] = ntld(crow + DH + 4);

#pragma unroll 2
  for (int ib = 0; ib < 16; ib++) {
    if (ib < 15) {
      const float* p = crow + (size_t)(2 * ib + 2) * DH;
      nxt[0] = ntld(p);
      nxt[1] = ntld(p + 4);
      nxt[2] = ntld(p + DH);
      nxt[3] = ntld(p + DH + 4);
    }
    const float* C = (const float*)cur;   // C[r*8+j], r in {0,1}

    float s0[2], s1[2];
#pragma unroll
    for (int r = 0; r < 2; r++) {
      float x0 = 0.f, x1 = 0.f;
#pragma unroll
      for (int j = 0; j < 8; j++) { x0 += C[r * 8 + j] * t0[j]; x1 += C[r * 8 + j] * t1[j]; }
      s0[r] = x0; s1[r] = x1;
    }
    // 4 independent butterfly chains (latency pipelined)
#pragma unroll
    for (int off = 32; off; off >>= 1) {
      s0[0] += __shfl_xor(s0[0], off);
      s0[1] += __shfl_xor(s0[1], off);
      s1[0] += __shfl_xor(s1[0], off);
      s1[1] += __shfl_xor(s1[1], off);
    }
#pragma unroll
    for (int r = 0; r < 2; r++)
      if (lane == 2 * ib + r) { sv0 = s0[r]; sv1 = s1[r]; }

    // k=0 amortized online-softmax update (branchless)
    {
      float mn = fmaxf(m0, fmaxf(s0[0], s0[1]));
      float al = __expf(m0 - mn);
      float p0 = __expf(s0[0] - mn), p1 = __expf(s0[1] - mn);
      l0 = l0 * al + p0 + p1;
      m0 = mn;
#pragma unroll
      for (int j = 0; j < 8; j++)
        a0[j] = a0[j] * al + p0 * C[j] + p1 * C[8 + j];
    }
    // k=1
    {
      float mn = fmaxf(m1, fmaxf(s1[0], s1[1]));
      float al = __expf(m1 - mn);
      float p0 = __expf(s1[0] - mn), p1 = __expf(s1[1] - mn);
      l1 = l1 * al + p0 + p1;
      m1 = mn;
#pragma unroll
      for (int j = 0; j < 8; j++)
        a1[j] = a1[j] * al + p0 * C[j] + p1 * C[8 + j];
    }
#pragma unroll
    for (int i = 0; i < 4; i++) cur[i] = nxt[i];
  }

  const int rowbase = b * NL + chunk * RPB + wave * RPW;
  if (lane < RPW) { sc0[rowbase + lane] = sv0; sc1[rowbase + lane] = sv1; }

  // merge 4 waves in LDS (epilogue, once per block: 4x ds_write_b128)
  __shared__ float accS[4][1024];
  __shared__ float mlS[4][4];
  *(float4*)&accS[wave][lane * 8]           = make_float4(a0[0], a0[1], a0[2], a0[3]);
  *(float4*)&accS[wave][lane * 8 + 4]       = make_float4(a0[4], a0[5], a0[6], a0[7]);
  *(float4*)&accS[wave][512 + lane * 8]     = make_float4(a1[0], a1[1], a1[2], a1[3]);
  *(float4*)&accS[wave][512 + lane * 8 + 4] = make_float4(a1[4], a1[5], a1[6], a1[7]);
  if (lane == 0) { mlS[wave][0] = m0; mlS[wave][1] = l0; mlS[wave][2] = m1; mlS[wave][3] = l1; }
  __syncthreads();

  const int t = threadIdx.x;
  const int k = (t * 4) >> 9;
  const int d = (t * 4) & 511;
  float M = fmaxf(fmaxf(mlS[0][2 * k], mlS[1][2 * k]), fmaxf(mlS[2][2 * k], mlS[3][2 * k]));
  float Lk = 0.f;
  float v0 = 0.f, v1 = 0.f, v2 = 0.f, v3 = 0.f;
#pragma unroll
  for (int w = 0; w < 4; w++) {
    float e = __expf(mlS[w][2 * k] - M);
    Lk += mlS[w][2 * k + 1] * e;
    const float* ap = &accS[w][k * 512 + d];
    v0 += ap[0] * e; v1 += ap[1] * e; v2 += ap[2] * e; v3 += ap[3] * e;
  }
  float* rec = part + ((size_t)(b * NCHUNK + chunk) * 2 + k) * REC;
  if ((t & 127) == 0) { rec[0] = M; rec[1] = Lk; }
  *(float4*)&rec[4 + d] = make_float4(v0, v1, v2, v3);
}

// ---------------------------------------------------------------------------
// Merge NCHUNK attn partials -> combined row [w0|w1|input]; normalize raw
// scores in place. Grid 256 = 64 b x 4 quadrants.
// ---------------------------------------------------------------------------
__global__ __launch_bounds__(256) void k3_combine(const float* __restrict__ part,
                                                  const float* __restrict__ inp,
                                                  float* __restrict__ combined,
                                                  float* __restrict__ sc0,
                                                  float* __restrict__ sc1) {
  const int b = blockIdx.x >> 2, q = blockIdx.x & 3;
  const int t = threadIdx.x;
  __shared__ float MM[2], LL[2];
  __shared__ float eS[2][NCHUNK];
  if (t < 2) {
    const int k = t;
    float Mk = -INFINITY;
#pragma unroll
    for (int c = 0; c < NCHUNK; c++)
      Mk = fmaxf(Mk, part[((size_t)(b * NCHUNK + c) * 2 + k) * REC]);
    float Lk = 0.f;
#pragma unroll
    for (int c = 0; c < NCHUNK; c++) {
      const float* rec = part + ((size_t)(b * NCHUNK + c) * 2 + k) * REC;
      Lk += rec[1] * __expf(rec[0] - Mk);
    }
    MM[k] = Mk; LL[k] = Lk;
  }
  __syncthreads();
  if (t < 2 * NCHUNK) {
    const int k = t >> 4, c = t & 15;
    eS[k][c] = __expf(part[((size_t)(b * NCHUNK + c) * 2 + k) * REC] - MM[k]);
  }
  __syncthreads();

  const int k = t >> 7, d = q * 128 + (t & 127);
  float v = 0.f;
#pragma unroll
  for (int c = 0; c < NCHUNK; c++)
    v += part[((size_t)(b * NCHUNK + c) * 2 + k) * REC + 4 + d] * eS[k][c];
  combined[(size_t)b * 2048 + k * 512 + d] = v / LL[k];

  combined[(size_t)b * 2048 + 1024 + q * 256 + t] = inp[(size_t)b * ND + q * 256 + t];

  const float M0 = MM[0], i0 = 1.f / LL[0];
  const float M1 = MM[1], i1 = 1.f / LL[1];
  const int pos = b * NL + q * 512 + t * 2;
  float2 x0 = *(const float2*)(sc0 + pos);
  float2 x1 = *(const float2*)(sc1 + pos);
  x0.x = __expf(x0.x - M0) * i0; x0.y = __expf(x0.y - M0) * i0;
  x1.x = __expf(x1.x - M1) * i1; x1.y = __expf(x1.y - M1) * i1;
  *(float2*)(sc0 + pos) = x0;
  *(float2*)(sc1 + pos) = x1;
}

// ---------------------------------------------------------------------------
extern "C" void kernel_launch(void* const* d_in, const int* in_sizes, int n_in,
                              void* d_out, int out_size, void* d_ws, size_t ws_size,
                              hipStream_t stream) {
  const float* input   = (const float*)d_in[0];   // [64,1024]
  const float* context = (const float*)d_in[1];   // [64,2048,512]
  const float* W_in    = (const float*)d_in[2];   // [1024,1024]
  const float* W_out   = (const float*)d_in[3];   // [1024,2048]

  float* out   = (float*)d_out;        // [64,1024] contextOutput
  float* attn0 = out + NB * ND;        // [64,2048]
  float* attn1 = attn0 + NB * NL;      // [64,2048]

  float* ws       = (float*)d_ws;
  float* target   = ws;                               // 64*1024
  float* combined = target + NB * ND;                 // 64*2048
  float* apart    = combined + NB * 2048;             // 64*16*2*520
  float* gpart    = apart + NB * NCHUNK * 2 * REC;    // KS*64*1024

  // 1) target = input @ W_in.T   (split-K partials + reduce)
  k_gemm<ND><<<dim3(32, KS), dim3(256), 0, stream>>>(input, W_in, gpart);
  k_reduce<0><<<dim3(256), dim3(64), 0, stream>>>(gpart, target);
  // 2) fused scores + online-softmax weighted partials (context read once)
  k2_attn<<<dim3(NCHUNK, NB), dim3(256), 0, stream>>>(context, target, attn0, attn1, apart);
  // 3) merge partials -> combined rows; normalize attn in place
  k3_combine<<<dim3(4 * NB), dim3(256), 0, stream>>>(apart, input, combined, attn0, attn1);
  // 4) out = tanh(combined @ W_out.T)
  k_gemm<2 * ND><<<dim3(32, KS), dim3(256), 0, stream>>>(combined, W_out, gpart);
  k_reduce<1><<<dim3(256), dim3(64), 0, stream>>>(gpart, out);
}